// Round 9
// baseline (2015.988 us; speedup 1.0000x reference)
//
#include <hip/hip_runtime.h>
#include <math.h>

#define DEVI __device__ __forceinline__

namespace {

constexpr int NN = 20000;
constexpr int NE = 640000;

typedef __attribute__((ext_vector_type(8))) short s8v;   // 8 x bf16 fragment
typedef __attribute__((ext_vector_type(4))) float f4v;   // 4 x f32 accumulator

DEVI float gelu_f(float x){ return 0.5f*x*(1.0f+erff(x*0.70710678118654752440f)); }
DEVI float gelu_t(float x){
  float u = x*x;
  float z = x*(1.59576912f + 0.07135481f*u);
  return x / (1.f + __expf(-z));
}
DEVI float sigm(float x){ return 1.0f/(1.0f+expf(-x)); }
DEVI float sigm_f(float x){ return 1.0f/(1.0f+__expf(-x)); }
DEVI unsigned bf_rne(float f){ unsigned u=__float_as_uint(f); return (u + 0x7fffu + ((u>>16)&1u)) >> 16; }

struct F3{ float x,y,z; };
DEVI F3 sub3(F3 a, F3 b){ return F3{a.x-b.x, a.y-b.y, a.z-b.z}; }
DEVI F3 cross3(F3 a, F3 b){ return F3{a.y*b.z-a.z*b.y, a.z*b.x-a.x*b.z, a.x*b.y-a.y*b.x}; }
DEVI F3 snorm3(F3 v){
  float n2 = v.x*v.x+v.y*v.y+v.z*v.z;
  if(n2 > 0.f){ float inv = 1.0f/sqrtf(n2); return F3{v.x*inv, v.y*inv, v.z*inv}; }
  return F3{0.f,0.f,0.f};
}

// ---- weight transposes + npW bf16 padded conversion, one launch ----
__global__ void k_prep(const float* __restrict__ npW, const float* __restrict__ noW,
                       const float* __restrict__ goW,
                       const float* __restrict__ mWss, const float* __restrict__ mWvs,
                       const float* __restrict__ uWss, const float* __restrict__ uWvs,
                       unsigned short* __restrict__ npW_bf, float* __restrict__ Wt_no,
                       float* __restrict__ Wt_go,
                       float* __restrict__ Wt_mss, float* __restrict__ Wt_mvs,
                       float* __restrict__ Wt_uss, float* __restrict__ Wt_uvs){
  int b = blockIdx.x, t = threadIdx.x;
  if(b >= 1563){
    int idx = (b-1563)*256 + t;
    if(idx < 128*1408){
      int r = idx/1408, c = idx-r*1408;
      npW_bf[idx] = (c<1289) ? (unsigned short)bf_rne(npW[(size_t)r*1289+c]) : (unsigned short)0;
    }
    return;
  }
  const float* src; float* dst; int R,C,ld,base,elems;
  if(b<640){ src=noW; dst=Wt_no; R=1280;C=128;ld=128; base=0; elems=163840; }
  else if(b<768){ src=goW; dst=Wt_go; R=256;C=128;ld=128; base=640; elems=32768; }
  else {
    int bb=b-768; int l=bb/265; int r=bb-l*265;
    if(r<128){ src=mWss+(size_t)l*128*384; dst=Wt_mss+(size_t)l*256*128; R=128;C=256;ld=384; base=768+l*265; elems=32768; }
    else if(r<133){ src=mWvs+(size_t)l*128*9; dst=Wt_mvs+(size_t)l*9*128; R=128;C=9;ld=9; base=768+l*265+128; elems=1152; }
    else if(r<261){ src=uWss+(size_t)l*128*256; dst=Wt_uss+(size_t)l*256*128; R=128;C=256;ld=256; base=768+l*265+133; elems=32768; }
    else { src=uWvs+(size_t)l*128*8; dst=Wt_uvs+(size_t)l*8*128; R=128;C=8;ld=8; base=768+l*265+261; elems=1024; }
  }
  int idx=(b-base)*256+t;
  if(idx>=elems) return;
  int r=idx/C, c=idx%C;
  dst[c*R+r] = src[r*ld+c];
}

// stream-convert [esm | geo_scalar | 0-pad] -> esm_bf [20000][1408] bf16
__global__ void k_conv(const float* __restrict__ esm, const float* __restrict__ geo,
                       unsigned short* __restrict__ esm_bf){
  int idx = blockIdx.x*256 + threadIdx.x;
  if(idx >= 20000*176) return;
  int r = idx/176, c = idx - r*176;
  int k = c*8;
  float v0,v1,v2,v3,v4,v5,v6,v7;
  if(k+8 <= 1280){
    const float4* p = reinterpret_cast<const float4*>(esm + (size_t)r*1280 + k);
    float4 x=p[0], y=p[1];
    v0=x.x;v1=x.y;v2=x.z;v3=x.w;v4=y.x;v5=y.y;v6=y.z;v7=y.w;
  } else {
    float vv[8];
#pragma unroll
    for(int j=0;j<8;j++){
      int kk=k+j;
      vv[j] = (kk<1280)? esm[(size_t)r*1280+kk] : ((kk<1289)? geo[r*15+6+(kk-1280)] : 0.f);
    }
    v0=vv[0];v1=vv[1];v2=vv[2];v3=vv[3];v4=vv[4];v5=vv[5];v6=vv[6];v7=vv[7];
  }
  uint4 w;
  w.x = bf_rne(v0) | (bf_rne(v1)<<16);
  w.y = bf_rne(v2) | (bf_rne(v3)<<16);
  w.z = bf_rne(v4) | (bf_rne(v5)<<16);
  w.w = bf_rne(v6) | (bf_rne(v7)<<16);
  reinterpret_cast<uint4*>(esm_bf)[idx] = w;
}

// node_s partials via bf16 MFMA, direct global->register, split-K x4.
__global__ __launch_bounds__(256,4) void k_init(
    const unsigned short* __restrict__ esm_bf, const unsigned short* __restrict__ npW_bf,
    float* __restrict__ part){
  int t = threadIdx.x;
  int b = blockIdx.x;
  int ks = b & 3, nb = b >> 2;
  int wv = t>>6, lane = t&63;
  int row0 = nb*64 + wv*16;
  int arow = row0 + (lane&15);
  int arc = (arow < NN) ? arow : (NN-1);
  int kb = (lane>>4)*8;
  const unsigned short* ap = esm_bf + (size_t)arc*1408 + ks*352 + kb;
  const unsigned short* bp = npW_bf + (size_t)(lane&15)*1408 + ks*352 + kb;
  f4v acc[8];
#pragma unroll
  for(int i=0;i<8;i++) acc[i] = (f4v){0.f,0.f,0.f,0.f};
  for(int c=0;c<11;c++){
    s8v a = *reinterpret_cast<const s8v*>(ap + c*32);
#pragma unroll
    for(int nt=0;nt<8;nt++){
      s8v bb = *reinterpret_cast<const s8v*>(bp + (size_t)nt*16*1408 + c*32);
      acc[nt] = __builtin_amdgcn_mfma_f32_16x16x32_bf16(a, bb, acc[nt], 0,0,0);
    }
  }
  float* po = part + (size_t)ks*NN*128;
  int col = lane&15, r4 = (lane>>4)*4;
#pragma unroll
  for(int nt=0;nt<8;nt++){
    int o = nt*16+col;
#pragma unroll
    for(int r=0;r<4;r++){
      int row = row0 + r4 + r;
      if(row<NN) po[(size_t)row*128+o] = acc[nt][r];
    }
  }
}

// node_s = bias + sum of 4 K-split partials (deterministic)
__global__ void k_reduce(const float* __restrict__ part, const float* __restrict__ bias,
                         float* __restrict__ node_s){
  int idx = blockIdx.x*256 + threadIdx.x;
  int o = idx & 127;
  node_s[idx] = bias[o] + part[idx] + part[(size_t)NN*128+idx]
              + part[2*(size_t)NN*128+idx] + part[3*(size_t)NN*128+idx];
}

// node geometric vectors; also zero the histogram buffers (runs before k_hist)
__global__ void k_nodevec(const float* __restrict__ coords, const float* __restrict__ geo,
                          float* __restrict__ node_v,
                          int* __restrict__ counts, int* __restrict__ cntg){
  int n = blockIdx.x*256 + threadIdx.x;
  if(n<64) cntg[n]=0;
  if(n>=NN) return;
  counts[n]=0;
  F3 c  {coords[n*3], coords[n*3+1], coords[n*3+2]};
  F3 cb {geo[n*15+3], geo[n*15+4], geo[n*15+5]};
  F3 cacb = snorm3(sub3(cb, c));
  F3 d{0.f,0.f,0.f};
  if(n < NN-1){
    F3 nx {coords[(n+1)*3], coords[(n+1)*3+1], coords[(n+1)*3+2]};
    d = snorm3(sub3(nx, c));
  }
  F3 nor = snorm3(cross3(cacb, d));
  F3 tv{0.f,0.f,0.f};
  if(n>0 && n<NN-1){
    F3 nx {coords[(n+1)*3], coords[(n+1)*3+1], coords[(n+1)*3+2]};
    F3 pv {coords[(n-1)*3], coords[(n-1)*3+1], coords[(n-1)*3+2]};
    tv = snorm3(sub3(nx, pv));
  }
  float* p = node_v + n*12;
  p[0]=cacb.x; p[1]=cacb.y; p[2]=cacb.z;
  p[3]=d.x;    p[4]=d.y;    p[5]=d.z;
  p[6]=nor.x;  p[7]=nor.y;  p[8]=nor.z;
  p[9]=tv.x;   p[10]=tv.y;  p[11]=tv.z;
}

__global__ void k_hist(const int* __restrict__ eidx, const int* __restrict__ batch,
                       int* __restrict__ counts, int* __restrict__ cntg){
  int i = blockIdx.x*256+threadIdx.x;
  if(i<NE) atomicAdd(&counts[eidx[NE+i]], 1);
  if(i<NN) atomicAdd(&cntg[batch[i]], 1);
}
__global__ void k_scan1(const int* __restrict__ counts, int* __restrict__ bsums){
  __shared__ int red[256];
  int b=blockIdx.x, t=threadIdx.x;
  int base=b*512;
  int v=0;
  for(int i=t;i<512;i+=256){ int g=base+i; if(g<NN) v+=counts[g]; }
  red[t]=v; __syncthreads();
  for(int s=128;s;s>>=1){ if(t<s) red[t]+=red[t+s]; __syncthreads(); }
  if(t==0) bsums[b]=red[0];
}
__global__ void k_scan23(const int* __restrict__ counts, const int* __restrict__ bsums,
                         int* __restrict__ offs, int* __restrict__ cursor){
  __shared__ int c_l[512];
  int b=blockIdx.x, t=threadIdx.x, base=b*512;
  for(int i=t;i<512;i+=256){ int g=base+i; c_l[i] = (g<NN)? counts[g]:0; }
  __syncthreads();
  if(t==0){
    int run=0;
    for(int i=0;i<b;i++) run += bsums[i];
    for(int i=0;i<512;i++){
      int g=base+i;
      if(g<NN){ offs[g]=run; cursor[g]=run; }
      run += c_l[i];
    }
    if(b==39) offs[NN]=run;
  }
}
__global__ void k_fill(const int* __restrict__ eidx, int* __restrict__ cursor,
                       const float* __restrict__ eattr,
                       int* __restrict__ srcp, float* __restrict__ ea_s){
  int e = blockIdx.x*256+threadIdx.x;
  if(e>=NE) return;
  int d = eidx[NE+e];
  int s = eidx[e];
  int pos = atomicAdd(&cursor[d], 1);
  srcp[pos] = s;
  const float4* src4 = reinterpret_cast<const float4*>(eattr + (size_t)e*16);
  float4* dst4 = reinterpret_cast<float4*>(ea_s + (size_t)pos*16);
  dst4[0]=src4[0]; dst4[1]=src4[1]; dst4[2]=src4[2]; dst4[3]=src4[3];
}

// P_a/P_b + per-node small precomputes (G, V) in one kernel.
__global__ __launch_bounds__(256,4) void k_pre(
                      const float* __restrict__ node_s, const float* __restrict__ node_v,
                      const float* __restrict__ Wt_ss, const float* __restrict__ Wt_vs,
                      const float* __restrict__ Wsv, const float* __restrict__ Wvv,
                      float* __restrict__ P_a, float* __restrict__ P_b,
                      float* __restrict__ G_a, float* __restrict__ G_b,
                      float* __restrict__ V_a, float* __restrict__ V_b){
  __shared__ float s_l[16][128];
  __shared__ float nv_l[16][4];
  __shared__ float uv[16][12];
  int t = threadIdx.x;
  int n0 = blockIdx.x*16;
  for(int idx=t; idx<2048; idx+=256){
    int n = idx>>7, k = idx&127;
    s_l[n][k] = node_s[(size_t)(n0+n)*128 + k];
  }
  if(t<192){ int n=t/12, k=t%12; uv[n][k] = node_v[(n0+n)*12+k]; }
  __syncthreads();
  if(t<64){
    int n=t>>2, j=t&3;
    float x=uv[n][j*3], y=uv[n][j*3+1], z=uv[n][j*3+2];
    float n2=x*x+y*y+z*z;
    nv_l[n][j] = n2>0.f ? sqrtf(n2) : 0.f;
  }
  if(t<192){
    int n=t/12, k=t%12, c=k/3, x=k-c*3;
    float va=0.f, vb=0.f;
#pragma unroll
    for(int j=0;j<4;j++){
      float vv = uv[n][j*3+x];
      va += Wvv[c*9+j]*vv;
      vb += Wvv[c*9+4+j]*vv;
    }
    V_a[(n0+n)*12+k]=va; V_b[(n0+n)*12+k]=vb;
  }
  if(t<128){
    int n=t>>3, c=(t>>1)&3, hh=t&1;
    const float* w = Wsv + c*384 + hh*128;
    float g=0.f;
    for(int k=0;k<128;k+=4){
      float4 s4 = *reinterpret_cast<const float4*>(&s_l[n][k]);
      g = fmaf(s4.x,w[k],g); g = fmaf(s4.y,w[k+1],g);
      g = fmaf(s4.z,w[k+2],g); g = fmaf(s4.w,w[k+3],g);
    }
    (hh ? G_b : G_a)[(n0+n)*4+c] = g;
  }
  __syncthreads();
  int o = t&127, h = t>>7;
  float acc[16];
#pragma unroll
  for(int i=0;i<16;i++) acc[i]=0.f;
  const float* Wb = Wt_ss + h*128*128;
  for(int k=0;k<128;k+=4){
    float w0=Wb[(k+0)*128+o], w1=Wb[(k+1)*128+o], w2=Wb[(k+2)*128+o], w3=Wb[(k+3)*128+o];
#pragma unroll
    for(int n=0;n<16;n++){
      float4 s4 = *reinterpret_cast<const float4*>(&s_l[n][k]);
      acc[n] = fmaf(s4.x,w0,acc[n]); acc[n] = fmaf(s4.y,w1,acc[n]);
      acc[n] = fmaf(s4.z,w2,acc[n]); acc[n] = fmaf(s4.w,w3,acc[n]);
    }
  }
  const float* Wv = Wt_vs + h*4*128;
#pragma unroll
  for(int j=0;j<4;j++){
    float w = Wv[j*128+o];
#pragma unroll
    for(int n=0;n<16;n++) acc[n] += nv_l[n][j]*w;
  }
  float* P = h ? P_b : P_a;
#pragma unroll
  for(int n=0;n<16;n++) P[(size_t)(n0+n)*128+o] = acc[n];
}

// edge-path constants folded through edge_proj, all 3 layers in one launch
__global__ void k_econst3(const float* __restrict__ mWss, const float* __restrict__ mWvs,
                          const float* __restrict__ mWsv, const float* __restrict__ mWvv,
                          const float* __restrict__ Wep, const float* __restrict__ epb,
                          float* __restrict__ econ){
  int l = blockIdx.x;
  const float* Wss = mWss + (size_t)l*128*384;
  const float* Wvs = mWvs + (size_t)l*128*9;
  const float* Wsv = mWsv + (size_t)l*4*384;
  const float* Wvv = mWvv + (size_t)l*4*9;
  float* ec = econ + (size_t)l*2048;
  int t=threadIdx.x;
  for(int idx=t; idx<13*128; idx+=256){
    int j=idx>>7, o=idx&127;
    float s=0.f;
    for(int k=0;k<128;k++) s += Wss[o*384+256+k]*Wep[k*13+j];
    ec[j*128+o]=s;
  }
  for(int o=t;o<128;o+=256){
    float s=0.f;
    for(int k=0;k<128;k++) s += Wss[o*384+256+k]*epb[k];
    ec[1664+o]=s;
    ec[1792+o]=Wvs[o*9+8];
  }
  if(t<52){ int c=t/13,j=t%13; float s=0.f; for(int k=0;k<128;k++) s+=Wsv[c*384+256+k]*Wep[k*13+j]; ec[1920+t]=s; }
  if(t<4){ float s=0.f; for(int k=0;k<128;k++) s+=Wsv[t*384+256+k]*epb[k]; ec[1972+t]=s; ec[1976+t]=Wvv[t*9+8]; }
}

// per-layer edge precompute: preS2[pos] = packed bf16 pair; preG[pos] = {gate[4], ev[3], 0}
__global__ __launch_bounds__(256,4) void k_edge(
    const float* __restrict__ ea_s, const float* __restrict__ ec,
    unsigned* __restrict__ preS2, float* __restrict__ preG){
  int t = threadIdx.x;
  int lane = t&63;
  int wid = blockIdx.x*4 + (t>>6);
  float mex[13], mey[13];
#pragma unroll
  for(int j=0;j<13;j++){ mex[j]=ec[j*128+lane]; mey[j]=ec[j*128+64+lane]; }
  float bx=ec[1664+lane], by=ec[1664+64+lane];
  float w8x=ec[1792+lane], w8y=ec[1792+64+lane];
  int cg = (lane<4)?lane:0;
  float grc[13];
#pragma unroll
  for(int j=0;j<13;j++) grc[j]=ec[1920+cg*13+j];
  float gb = ec[1972+cg];
  int e00 = wid*8;
#pragma unroll 2
  for(int i=0;i<8;i++){
    int e = e00+i;
    const float4* ea = reinterpret_cast<const float4*>(ea_s + e*16);
    float4 A0=ea[0], A1=ea[1], A2=ea[2], A3=ea[3];
    float e0=A0.x,e1=A0.y,e2=A1.y,e3=A1.z,e4=A1.w,
          e5=A2.x,e6=A2.y,e7=A2.z,e8=A2.w,e9=A3.x,
          e10=A3.y,e11=A3.z,e12=A3.w;
    float evx=A0.z, evy=A0.w, evz=A1.x;
    float en2 = evx*evx+evy*evy+evz*evz;
    float evn = en2>0.f ? sqrtf(en2) : 0.f;
    float px = fmaf(evn,w8x,bx);
    float py = fmaf(evn,w8y,by);
    px=fmaf(mex[0],e0,px);   py=fmaf(mey[0],e0,py);
    px=fmaf(mex[1],e1,px);   py=fmaf(mey[1],e1,py);
    px=fmaf(mex[2],e2,px);   py=fmaf(mey[2],e2,py);
    px=fmaf(mex[3],e3,px);   py=fmaf(mey[3],e3,py);
    px=fmaf(mex[4],e4,px);   py=fmaf(mey[4],e4,py);
    px=fmaf(mex[5],e5,px);   py=fmaf(mey[5],e5,py);
    px=fmaf(mex[6],e6,px);   py=fmaf(mey[6],e6,py);
    px=fmaf(mex[7],e7,px);   py=fmaf(mey[7],e7,py);
    px=fmaf(mex[8],e8,px);   py=fmaf(mey[8],e8,py);
    px=fmaf(mex[9],e9,px);   py=fmaf(mey[9],e9,py);
    px=fmaf(mex[10],e10,px); py=fmaf(mey[10],e10,py);
    px=fmaf(mex[11],e11,px); py=fmaf(mey[11],e11,py);
    px=fmaf(mex[12],e12,px); py=fmaf(mey[12],e12,py);
    preS2[e*64+lane] = bf_rne(px) | (bf_rne(py)<<16);
    if(lane<4){
      float g=gb;
      g=fmaf(grc[0],e0,g);  g=fmaf(grc[1],e1,g);  g=fmaf(grc[2],e2,g);
      g=fmaf(grc[3],e3,g);  g=fmaf(grc[4],e4,g);  g=fmaf(grc[5],e5,g);
      g=fmaf(grc[6],e6,g);  g=fmaf(grc[7],e7,g);  g=fmaf(grc[8],e8,g);
      g=fmaf(grc[9],e9,g);  g=fmaf(grc[10],e10,g); g=fmaf(grc[11],e11,g);
      g=fmaf(grc[12],e12,g);
      preG[e*8+lane] = g;
    } else if(lane<7){
      float evv = (lane==4)?evx:((lane==5)?evy:evz);
      preG[e*8+lane] = evv;
    }
  }
}

// skinny gather kernel: one wave per destination node (int32 indices, high occupancy)
#define DECLST(P) unsigned P##w=0; float P##pax=0.f,P##pay=0.f,P##g8=0.f,P##ev=0.f,P##ga=0.f,P##va=0.f;
#define LOADST(P, IDX) do{ int _p=(IDX); int _s=srcp[_p]; \
  P##w   = preS2[_p*64 + lane]; \
  P##pax = P_a[_s*128+lane]; P##pay = P_a[_s*128+64+lane]; \
  if(lane<12){ P##g8 = preG[_p*8+cv]; P##ev = preG[_p*8+4+xv]; \
               P##ga = G_a[_s*4+cv];  P##va = V_a[_s*12+lane]; } \
}while(0)
#define COMPUTE(P) do{ \
  float px = __uint_as_float(P##w<<16); \
  float py = __uint_as_float(P##w & 0xffff0000u); \
  float pre0 = px + P##pax + PBx; \
  float pre1 = py + P##pay + PBy; \
  float sm = pre0+pre1; \
  float sq = pre0*pre0 + pre1*pre1; \
  _Pragma("unroll") \
  for(int m=32;m;m>>=1){ sm += __shfl_xor(sm,m); sq += __shfl_xor(sq,m); } \
  float mean = sm*0.0078125f; \
  float var  = fmaf(sq,0.0078125f, -mean*mean); \
  float rstd = rsqrtf((var>0.f?var:0.f) + 1e-5f); \
  accx += gelu_t(fmaf((pre0-mean)*rstd, LGx, LBx)); \
  accy += gelu_t(fmaf((pre1-mean)*rstd, LGy, LBy)); \
  if(lane<12){ \
    float g = P##g8 + P##ga + gbn; \
    float gt = sigm_f(g); \
    avk = fmaf(fmaf(wvc, P##ev, P##va + vbk), gt, avk); \
  } \
}while(0)

__global__ __launch_bounds__(256,8) void k_msg(
                      const float* __restrict__ P_a, const float* __restrict__ P_b,
                      const float* __restrict__ G_a, const float* __restrict__ G_b,
                      const float* __restrict__ V_a, const float* __restrict__ V_b,
                      const unsigned* __restrict__ preS2, const float* __restrict__ preG,
                      const int* __restrict__ srcp, const int* __restrict__ offs,
                      const float* __restrict__ ec,
                      const float* __restrict__ lng, const float* __restrict__ lnb,
                      float* __restrict__ ag_s, float* __restrict__ ag_v){
  int t = threadIdx.x;
  int n = blockIdx.x*4 + (t>>6);
  int lane = t&63;
  float PBx = P_b[n*128+lane], PBy = P_b[n*128+64+lane];
  float LGx = lng[lane], LGy = lng[64+lane];
  float LBx = lnb[lane], LBy = lnb[64+lane];
  int cv = lane/3, xv = lane - cv*3;
  float vbk=0.f, gbn=0.f, wvc=0.f;
  if(lane<12){
    vbk = V_b[n*12+lane];
    gbn = G_b[n*4+cv];
    wvc = ec[1976+cv];
  }
  float accx=0.f, accy=0.f, avk=0.f;
  int beg = offs[n], end = offs[n+1];
  DECLST(a_) DECLST(b_)
  int idx = beg;
  if(beg < end) LOADST(a_, beg);
  while(idx + 1 < end){
    LOADST(b_, idx+1);
    COMPUTE(a_);
    if(idx + 2 < end) LOADST(a_, idx+2);
    COMPUTE(b_);
    idx += 2;
  }
  if(idx < end) COMPUTE(a_);
  ag_s[n*128+lane]    = accx;
  ag_s[n*128+64+lane] = accy;
  if(lane<12) ag_v[n*12+lane] = avk;
}

// node update GVP (residual)
__global__ __launch_bounds__(256,4) void k_update(
                         float* __restrict__ node_s, float* __restrict__ node_v,
                         const float* __restrict__ ag_s, const float* __restrict__ ag_v,
                         const float* __restrict__ Wt_ss, const float* __restrict__ Wt_vs,
                         const float* __restrict__ Wsv, const float* __restrict__ Wvv,
                         const float* __restrict__ lng, const float* __restrict__ lnb){
  __shared__ float us[16][260];
  __shared__ float pre[16][129];
  __shared__ float uv[16][24];
  __shared__ float uvn[16][8];
  __shared__ float stats[16][2];
  __shared__ float gate_l[16][4];
  int t = threadIdx.x;
  int n0 = blockIdx.x*16;
  for(int idx=t; idx<2048; idx+=256){
    int n = idx>>7, k = idx&127;
    us[n][k]     = node_s[(size_t)(n0+n)*128+k];
    us[n][128+k] = ag_s[(size_t)(n0+n)*128+k];
  }
  for(int idx=t; idx<384; idx+=256){
    int n = idx/24, k = idx%24;
    uv[n][k] = (k<12) ? node_v[(n0+n)*12+k] : ag_v[(n0+n)*12 + (k-12)];
  }
  __syncthreads();
  if(t<128){
    int n=t>>3, j=t&7;
    float x=uv[n][j*3], y=uv[n][j*3+1], z=uv[n][j*3+2];
    float n2=x*x+y*y+z*z;
    uvn[n][j] = n2>0.f ? sqrtf(n2) : 0.f;
  }
  __syncthreads();
  int o = t&127, h = t>>7;
  float acc[8];
#pragma unroll
  for(int i=0;i<8;i++) acc[i]=0.f;
  for(int k=0;k<256;k+=4){
    float w0=Wt_ss[(k+0)*128+o], w1=Wt_ss[(k+1)*128+o], w2=Wt_ss[(k+2)*128+o], w3=Wt_ss[(k+3)*128+o];
#pragma unroll
    for(int i=0;i<8;i++){
      float4 s4 = *reinterpret_cast<const float4*>(&us[h*8+i][k]);
      acc[i] = fmaf(s4.x,w0,acc[i]); acc[i] = fmaf(s4.y,w1,acc[i]);
      acc[i] = fmaf(s4.z,w2,acc[i]); acc[i] = fmaf(s4.w,w3,acc[i]);
    }
  }
#pragma unroll
  for(int j=0;j<8;j++){
    float w = Wt_vs[j*128+o];
#pragma unroll
    for(int i=0;i<8;i++) acc[i] += uvn[h*8+i][j]*w;
  }
#pragma unroll
  for(int i=0;i<8;i++) pre[h*8+i][o] = acc[i];
  __syncthreads();
  {
    int n = t>>4, p = t&15;
    float s=0.f;
#pragma unroll
    for(int q=0;q<8;q++) s += pre[n][p*8+q];
#pragma unroll
    for(int m=8;m;m>>=1) s += __shfl_xor(s,m);
    float mean = s*(1.f/128.f);
    float v=0.f;
#pragma unroll
    for(int q=0;q<8;q++){ float d=pre[n][p*8+q]-mean; v += d*d; }
#pragma unroll
    for(int m=8;m;m>>=1) v += __shfl_xor(v,m);
    if(p==0){ stats[n][0]=mean; stats[n][1]=rsqrtf(v*(1.f/128.f)+1e-5f); }
  }
  __syncthreads();
  {
    float LG = lng[o], LB = lnb[o];
#pragma unroll
    for(int i=0;i<8;i++){
      int n = h*8+i;
      float hh = (pre[n][o]-stats[n][0])*stats[n][1]*LG + LB;
      node_s[(size_t)(n0+n)*128+o] += gelu_f(hh);
    }
  }
  {
    int n = t>>4, c = t&3, p = (t>>2)&3;
    float g=0.f;
    int kb = p*64;
    for(int k=0;k<64;k+=4){
      float4 s4 = *reinterpret_cast<const float4*>(&us[n][kb+k]);
      g = fmaf(s4.x,Wsv[c*256+kb+k],g);   g = fmaf(s4.y,Wsv[c*256+kb+k+1],g);
      g = fmaf(s4.z,Wsv[c*256+kb+k+2],g); g = fmaf(s4.w,Wsv[c*256+kb+k+3],g);
    }
    g += __shfl_xor(g,4);
    g += __shfl_xor(g,8);
    if(p==0) gate_l[n][c] = sigm(g);
  }
  __syncthreads();
  if(t<192){
    int n = t/12, k = t%12, c = k/3, x = k-c*3;
    float s=0.f;
#pragma unroll
    for(int j=0;j<8;j++) s += Wvv[c*8+j]*uv[n][j*3+x];
    node_v[(n0+n)*12+k] += s*gate_l[n][c];
  }
}

// updated_nodes = node_s @ noW.T + b ; block = 32 rows x 256 cols, thread = 8n x 4o.
__global__ __launch_bounds__(256,8) void k_out(
    const float* __restrict__ node_s, const float* __restrict__ Wt_no,
    const float* __restrict__ nob, float* __restrict__ out){
  __shared__ float s_l[32][132];
  int t = threadIdx.x;
  int n0 = blockIdx.x*32;
  int oc0 = blockIdx.y*256;
  {
    const float4* g = reinterpret_cast<const float4*>(node_s + (size_t)n0*128);
    for(int i=t;i<1024;i+=256){
      int n=i>>5, kq=i&31;
      *reinterpret_cast<float4*>(&s_l[n][kq*4]) = g[i];
    }
  }
  __syncthreads();
  int oq = t&63, ng = t>>6;
  int o = oc0 + oq*4;
  float4 acc[8];
#pragma unroll
  for(int i=0;i<8;i++) acc[i]=float4{0.f,0.f,0.f,0.f};
  for(int k=0;k<128;k+=4){
    float4 w0 = *reinterpret_cast<const float4*>(&Wt_no[(k+0)*1280+o]);
    float4 w1 = *reinterpret_cast<const float4*>(&Wt_no[(k+1)*1280+o]);
    float4 w2 = *reinterpret_cast<const float4*>(&Wt_no[(k+2)*1280+o]);
    float4 w3 = *reinterpret_cast<const float4*>(&Wt_no[(k+3)*1280+o]);
#pragma unroll
    for(int i=0;i<8;i++){
      float4 s = *reinterpret_cast<const float4*>(&s_l[ng*8+i][k]);
      acc[i].x=fmaf(s.x,w0.x,acc[i].x); acc[i].y=fmaf(s.x,w0.y,acc[i].y);
      acc[i].z=fmaf(s.x,w0.z,acc[i].z); acc[i].w=fmaf(s.x,w0.w,acc[i].w);
      acc[i].x=fmaf(s.y,w1.x,acc[i].x); acc[i].y=fmaf(s.y,w1.y,acc[i].y);
      acc[i].z=fmaf(s.y,w1.z,acc[i].z); acc[i].w=fmaf(s.y,w1.w,acc[i].w);
      acc[i].x=fmaf(s.z,w2.x,acc[i].x); acc[i].y=fmaf(s.z,w2.y,acc[i].y);
      acc[i].z=fmaf(s.z,w2.z,acc[i].z); acc[i].w=fmaf(s.z,w2.w,acc[i].w);
      acc[i].x=fmaf(s.w,w3.x,acc[i].x); acc[i].y=fmaf(s.w,w3.y,acc[i].y);
      acc[i].z=fmaf(s.w,w3.z,acc[i].z); acc[i].w=fmaf(s.w,w3.w,acc[i].w);
    }
  }
  float4 b4 = *reinterpret_cast<const float4*>(&nob[o]);
#pragma unroll
  for(int i=0;i<8;i++){
    int row = n0 + ng*8 + i;
    float4 r{acc[i].x+b4.x, acc[i].y+b4.y, acc[i].z+b4.z, acc[i].w+b4.w};
    *reinterpret_cast<float4*>(&out[16384 + (size_t)row*1280 + o]) = r;
  }
}

// graph-feature partial sums (sorted-run compressed atomics)
__global__ __launch_bounds__(256,4) void k_gfeat(
                        const float* __restrict__ node_s, const float* __restrict__ Wt,
                        const int* __restrict__ batch, float* __restrict__ gacc){
  __shared__ float s_l[16][128];
  __shared__ int b_l[16];
  int t=threadIdx.x, n0=blockIdx.x*16;
  for(int idx=t; idx<2048; idx+=256){ int n=idx>>7,k=idx&127; s_l[n][k]=node_s[(size_t)(n0+n)*128+k]; }
  if(t<16) b_l[t]=batch[n0+t];
  __syncthreads();
  int o=t;
  float acc[16];
#pragma unroll
  for(int i=0;i<16;i++) acc[i]=0.f;
  for(int k=0;k<128;k+=4){
    float w0=Wt[(k+0)*256+o], w1=Wt[(k+1)*256+o], w2=Wt[(k+2)*256+o], w3=Wt[(k+3)*256+o];
#pragma unroll
    for(int n=0;n<16;n++){
      float4 s4 = *reinterpret_cast<const float4*>(&s_l[n][k]);
      acc[n] = fmaf(s4.x,w0,acc[n]); acc[n] = fmaf(s4.y,w1,acc[n]);
      acc[n] = fmaf(s4.z,w2,acc[n]); acc[n] = fmaf(s4.w,w3,acc[n]);
    }
  }
  float run=0.f; int cur=b_l[0];
#pragma unroll
  for(int n=0;n<16;n++){
    int g=b_l[n];
    if(g!=cur){ atomicAdd(&gacc[cur*256+o], run); run=0.f; cur=g; }
    run += acc[n];
  }
  atomicAdd(&gacc[cur*256+o], run);
}

__global__ void k_gfin(const float* __restrict__ gacc, const int* __restrict__ cntg,
                       const float* __restrict__ gob, float* __restrict__ out){
  int g=blockIdx.x, o=threadIdx.x;
  int c=cntg[g];
  out[g*256+o] = (c>0) ? (gacc[g*256+o]/(float)c + gob[o]) : 0.f;
}

} // namespace

extern "C" void kernel_launch(void* const* d_in, const int* in_sizes, int n_in,
                              void* d_out, int out_size, void* d_ws, size_t ws_size,
                              hipStream_t stream){
  (void)in_sizes; (void)n_in; (void)out_size;
  const float* esm   = (const float*)d_in[0];
  const float* geo   = (const float*)d_in[1];
  const float* coords= (const float*)d_in[2];
  const int*   eidx  = (const int*)d_in[3];
  const float* eattr = (const float*)d_in[4];
  const int*   batch = (const int*)d_in[5];
  const float* npW   = (const float*)d_in[6];
  const float* npb   = (const float*)d_in[7];
  const float* epW   = (const float*)d_in[8];
  const float* epb   = (const float*)d_in[9];
  const float* mWss  = (const float*)d_in[10];
  const float* mWvs  = (const float*)d_in[11];
  const float* mWsv  = (const float*)d_in[12];
  const float* mWvv  = (const float*)d_in[13];
  const float* mlg   = (const float*)d_in[14];
  const float* mlb   = (const float*)d_in[15];
  const float* uWss  = (const float*)d_in[16];
  const float* uWvs  = (const float*)d_in[17];
  const float* uWsv  = (const float*)d_in[18];
  const float* uWvv  = (const float*)d_in[19];
  const float* ulg   = (const float*)d_in[20];
  const float* ulb   = (const float*)d_in[21];
  const float* noW   = (const float*)d_in[22];
  const float* nob   = (const float*)d_in[23];
  const float* goW   = (const float*)d_in[24];
  const float* gob   = (const float*)d_in[25];
  float* out = (float*)d_out;

  char* base = (char*)d_ws;
  size_t off = 0;
  auto ALLOC = [&](size_t bytes)->char*{
    char* p = base + off;
    off = (off + bytes + 255) & ~(size_t)255;
    return p;
  };
  float* node_s = (float*)ALLOC((size_t)NN*128*4);
  float* P_a    = (float*)ALLOC((size_t)NN*128*4);
  float* P_b    = (float*)ALLOC((size_t)NN*128*4);
  float* ag_s   = (float*)ALLOC((size_t)NN*128*4);
  float* node_v = (float*)ALLOC((size_t)NN*12*4);
  float* ag_v   = (float*)ALLOC((size_t)NN*12*4);
  float* V_a    = (float*)ALLOC((size_t)NN*12*4);
  float* V_b    = (float*)ALLOC((size_t)NN*12*4);
  float* G_a    = (float*)ALLOC((size_t)NN*4*4);
  float* G_b    = (float*)ALLOC((size_t)NN*4*4);
  unsigned short* npW_bf = (unsigned short*)ALLOC((size_t)128*1408*2);
  unsigned short* esm_bf = (unsigned short*)ALLOC((size_t)NN*1408*2);
  float* Wt_no  = (float*)ALLOC((size_t)128*1280*4);
  float* Wt_go  = (float*)ALLOC((size_t)128*256*4);
  float* Wt_mss = (float*)ALLOC((size_t)3*256*128*4);
  float* Wt_mvs = (float*)ALLOC((size_t)3*9*128*4);
  float* Wt_uss = (float*)ALLOC((size_t)3*256*128*4);
  float* Wt_uvs = (float*)ALLOC((size_t)3*8*128*4);
  float* econ   = (float*)ALLOC((size_t)3*2048*4);
  float* gacc   = (float*)ALLOC((size_t)64*256*4);
  int* counts = (int*)ALLOC((size_t)NN*4);
  int* offs   = (int*)ALLOC((size_t)(NN+1)*4);
  int* cursor = (int*)ALLOC((size_t)NN*4);
  int* bsums  = (int*)ALLOC((size_t)64*4);
  int* cntg   = (int*)ALLOC((size_t)64*4);
  int* srcp   = (int*)ALLOC((size_t)NE*4);
  float* ea_s = (float*)ALLOC((size_t)NE*16*4);
  unsigned* preS2 = (unsigned*)ALLOC((size_t)NE*64*4);
  float* preG     = (float*)ALLOC((size_t)NE*8*4);
  if(off > ws_size) return;
  // k-split partials alias preS2 (consumed by k_reduce before k_edge writes preS2)
  float* part = (float*)preS2;

  hipMemsetAsync(gacc, 0, (size_t)64*256*4, stream);

  k_prep<<<2267,256,0,stream>>>(npW, noW, goW, mWss, mWvs, uWss, uWvs,
                                npW_bf, Wt_no, Wt_go, Wt_mss, Wt_mvs, Wt_uss, Wt_uvs);
  k_conv<<<13750,256,0,stream>>>(esm, geo, esm_bf);
  k_init<<<1252,256,0,stream>>>(esm_bf, npW_bf, part);
  k_reduce<<<10000,256,0,stream>>>(part, npb, node_s);
  k_nodevec<<<79,256,0,stream>>>(coords, geo, node_v, counts, cntg);
  k_hist<<<2500,256,0,stream>>>(eidx, batch, counts, cntg);
  k_scan1<<<40,256,0,stream>>>(counts, bsums);
  k_scan23<<<40,256,0,stream>>>(counts, bsums, offs, cursor);
  k_fill<<<2500,256,0,stream>>>(eidx, cursor, eattr, srcp, ea_s);
  k_econst3<<<3,256,0,stream>>>(mWss, mWvs, mWsv, mWvv, epW, epb, econ);

  for(int l=0;l<3;l++){
    k_pre<<<1250,256,0,stream>>>(node_s, node_v,
                                 Wt_mss + (size_t)l*256*128, Wt_mvs + (size_t)l*9*128,
                                 mWsv + (size_t)l*4*384, mWvv + (size_t)l*4*9,
                                 P_a, P_b, G_a, G_b, V_a, V_b);
    k_edge<<<20000,256,0,stream>>>(ea_s, econ + (size_t)l*2048, preS2, preG);
    k_msg<<<5000,256,0,stream>>>(P_a, P_b, G_a, G_b, V_a, V_b, preS2, preG, srcp, offs,
                                 econ + (size_t)l*2048, mlg + (size_t)l*128, mlb + (size_t)l*128,
                                 ag_s, ag_v);
    k_update<<<1250,256,0,stream>>>(node_s, node_v, ag_s, ag_v,
                                    Wt_uss + (size_t)l*256*128, Wt_uvs + (size_t)l*8*128,
                                    uWsv + (size_t)l*4*256, uWvv + (size_t)l*4*8,
                                    ulg + (size_t)l*128, ulb + (size_t)l*128);
  }
  k_out<<<dim3(625,5),256,0,stream>>>(node_s, Wt_no, nob, out);
  k_gfeat<<<1250,256,0,stream>>>(node_s, Wt_go, batch, gacc);
  k_gfin<<<64,256,0,stream>>>(gacc, cntg, gob, out);
}

// Round 10
// 1543.338 us; speedup vs baseline: 1.3063x; 1.3063x over previous
//
#include <hip/hip_runtime.h>
#include <math.h>

#define DEVI __device__ __forceinline__

namespace {

constexpr int NN = 20000;
constexpr int NE = 640000;

typedef __attribute__((ext_vector_type(8))) short s8v;   // 8 x bf16 fragment
typedef __attribute__((ext_vector_type(4))) float f4v;   // 4 x f32 accumulator

DEVI float gelu_f(float x){ return 0.5f*x*(1.0f+erff(x*0.70710678118654752440f)); }
DEVI float gelu_t(float x){
  float u = x*x;
  float z = x*(1.59576912f + 0.07135481f*u);
  return x / (1.f + __expf(-z));
}
DEVI float sigm(float x){ return 1.0f/(1.0f+expf(-x)); }
DEVI float sigm_f(float x){ return 1.0f/(1.0f+__expf(-x)); }
DEVI unsigned bf_rne(float f){ unsigned u=__float_as_uint(f); return (u + 0x7fffu + ((u>>16)&1u)) >> 16; }

struct F3{ float x,y,z; };
DEVI F3 sub3(F3 a, F3 b){ return F3{a.x-b.x, a.y-b.y, a.z-b.z}; }
DEVI F3 cross3(F3 a, F3 b){ return F3{a.y*b.z-a.z*b.y, a.z*b.x-a.x*b.z, a.x*b.y-a.y*b.x}; }
DEVI F3 snorm3(F3 v){
  float n2 = v.x*v.x+v.y*v.y+v.z*v.z;
  if(n2 > 0.f){ float inv = 1.0f/sqrtf(n2); return F3{v.x*inv, v.y*inv, v.z*inv}; }
  return F3{0.f,0.f,0.f};
}

// ---- weight transposes + npW bf16 padded conversion, one launch ----
__global__ void k_prep(const float* __restrict__ npW, const float* __restrict__ noW,
                       const float* __restrict__ goW,
                       const float* __restrict__ mWss, const float* __restrict__ mWvs,
                       const float* __restrict__ uWss, const float* __restrict__ uWvs,
                       unsigned short* __restrict__ npW_bf, float* __restrict__ Wt_no,
                       float* __restrict__ Wt_go,
                       float* __restrict__ Wt_mss, float* __restrict__ Wt_mvs,
                       float* __restrict__ Wt_uss, float* __restrict__ Wt_uvs){
  int b = blockIdx.x, t = threadIdx.x;
  if(b >= 1563){
    int idx = (b-1563)*256 + t;
    if(idx < 128*1408){
      int r = idx/1408, c = idx-r*1408;
      npW_bf[idx] = (c<1289) ? (unsigned short)bf_rne(npW[(size_t)r*1289+c]) : (unsigned short)0;
    }
    return;
  }
  const float* src; float* dst; int R,C,ld,base,elems;
  if(b<640){ src=noW; dst=Wt_no; R=1280;C=128;ld=128; base=0; elems=163840; }
  else if(b<768){ src=goW; dst=Wt_go; R=256;C=128;ld=128; base=640; elems=32768; }
  else {
    int bb=b-768; int l=bb/265; int r=bb-l*265;
    if(r<128){ src=mWss+(size_t)l*128*384; dst=Wt_mss+(size_t)l*256*128; R=128;C=256;ld=384; base=768+l*265; elems=32768; }
    else if(r<133){ src=mWvs+(size_t)l*128*9; dst=Wt_mvs+(size_t)l*9*128; R=128;C=9;ld=9; base=768+l*265+128; elems=1152; }
    else if(r<261){ src=uWss+(size_t)l*128*256; dst=Wt_uss+(size_t)l*256*128; R=128;C=256;ld=256; base=768+l*265+133; elems=32768; }
    else { src=uWvs+(size_t)l*128*8; dst=Wt_uvs+(size_t)l*8*128; R=128;C=8;ld=8; base=768+l*265+261; elems=1024; }
  }
  int idx=(b-base)*256+t;
  if(idx>=elems) return;
  int r=idx/C, c=idx%C;
  dst[c*R+r] = src[r*ld+c];
}

// stream-convert [esm | geo_scalar | 0-pad] -> esm_bf [20000][1408] bf16
__global__ void k_conv(const float* __restrict__ esm, const float* __restrict__ geo,
                       unsigned short* __restrict__ esm_bf){
  int idx = blockIdx.x*256 + threadIdx.x;
  if(idx >= 20000*176) return;
  int r = idx/176, c = idx - r*176;
  int k = c*8;
  float v0,v1,v2,v3,v4,v5,v6,v7;
  if(k+8 <= 1280){
    const float4* p = reinterpret_cast<const float4*>(esm + (size_t)r*1280 + k);
    float4 x=p[0], y=p[1];
    v0=x.x;v1=x.y;v2=x.z;v3=x.w;v4=y.x;v5=y.y;v6=y.z;v7=y.w;
  } else {
    float vv[8];
#pragma unroll
    for(int j=0;j<8;j++){
      int kk=k+j;
      vv[j] = (kk<1280)? esm[(size_t)r*1280+kk] : ((kk<1289)? geo[r*15+6+(kk-1280)] : 0.f);
    }
    v0=vv[0];v1=vv[1];v2=vv[2];v3=vv[3];v4=vv[4];v5=vv[5];v6=vv[6];v7=vv[7];
  }
  uint4 w;
  w.x = bf_rne(v0) | (bf_rne(v1)<<16);
  w.y = bf_rne(v2) | (bf_rne(v3)<<16);
  w.z = bf_rne(v4) | (bf_rne(v5)<<16);
  w.w = bf_rne(v6) | (bf_rne(v7)<<16);
  reinterpret_cast<uint4*>(esm_bf)[idx] = w;
}

// node_s partials via bf16 MFMA, direct global->register, split-K x4.
__global__ __launch_bounds__(256,4) void k_init(
    const unsigned short* __restrict__ esm_bf, const unsigned short* __restrict__ npW_bf,
    float* __restrict__ part){
  int t = threadIdx.x;
  int b = blockIdx.x;
  int ks = b & 3, nb = b >> 2;
  int wv = t>>6, lane = t&63;
  int row0 = nb*64 + wv*16;
  int arow = row0 + (lane&15);
  int arc = (arow < NN) ? arow : (NN-1);
  int kb = (lane>>4)*8;
  const unsigned short* ap = esm_bf + (size_t)arc*1408 + ks*352 + kb;
  const unsigned short* bp = npW_bf + (size_t)(lane&15)*1408 + ks*352 + kb;
  f4v acc[8];
#pragma unroll
  for(int i=0;i<8;i++) acc[i] = (f4v){0.f,0.f,0.f,0.f};
  for(int c=0;c<11;c++){
    s8v a = *reinterpret_cast<const s8v*>(ap + c*32);
#pragma unroll
    for(int nt=0;nt<8;nt++){
      s8v bb = *reinterpret_cast<const s8v*>(bp + (size_t)nt*16*1408 + c*32);
      acc[nt] = __builtin_amdgcn_mfma_f32_16x16x32_bf16(a, bb, acc[nt], 0,0,0);
    }
  }
  float* po = part + (size_t)ks*NN*128;
  int col = lane&15, r4 = (lane>>4)*4;
#pragma unroll
  for(int nt=0;nt<8;nt++){
    int o = nt*16+col;
#pragma unroll
    for(int r=0;r<4;r++){
      int row = row0 + r4 + r;
      if(row<NN) po[(size_t)row*128+o] = acc[nt][r];
    }
  }
}

// node_s = bias + sum of 4 K-split partials (deterministic)
__global__ void k_reduce(const float* __restrict__ part, const float* __restrict__ bias,
                         float* __restrict__ node_s){
  int idx = blockIdx.x*256 + threadIdx.x;
  int o = idx & 127;
  node_s[idx] = bias[o] + part[idx] + part[(size_t)NN*128+idx]
              + part[2*(size_t)NN*128+idx] + part[3*(size_t)NN*128+idx];
}

// node geometric vectors; also zero the histogram buffers (runs before k_hist)
__global__ void k_nodevec(const float* __restrict__ coords, const float* __restrict__ geo,
                          float* __restrict__ node_v,
                          int* __restrict__ counts, int* __restrict__ cntg){
  int n = blockIdx.x*256 + threadIdx.x;
  if(n<64) cntg[n]=0;
  if(n>=NN) return;
  counts[n]=0;
  F3 c  {coords[n*3], coords[n*3+1], coords[n*3+2]};
  F3 cb {geo[n*15+3], geo[n*15+4], geo[n*15+5]};
  F3 cacb = snorm3(sub3(cb, c));
  F3 d{0.f,0.f,0.f};
  if(n < NN-1){
    F3 nx {coords[(n+1)*3], coords[(n+1)*3+1], coords[(n+1)*3+2]};
    d = snorm3(sub3(nx, c));
  }
  F3 nor = snorm3(cross3(cacb, d));
  F3 tv{0.f,0.f,0.f};
  if(n>0 && n<NN-1){
    F3 nx {coords[(n+1)*3], coords[(n+1)*3+1], coords[(n+1)*3+2]};
    F3 pv {coords[(n-1)*3], coords[(n-1)*3+1], coords[(n-1)*3+2]};
    tv = snorm3(sub3(nx, pv));
  }
  float* p = node_v + n*12;
  p[0]=cacb.x; p[1]=cacb.y; p[2]=cacb.z;
  p[3]=d.x;    p[4]=d.y;    p[5]=d.z;
  p[6]=nor.x;  p[7]=nor.y;  p[8]=nor.z;
  p[9]=tv.x;   p[10]=tv.y;  p[11]=tv.z;
}

__global__ void k_hist(const int* __restrict__ eidx, const int* __restrict__ batch,
                       int* __restrict__ counts, int* __restrict__ cntg){
  int i = blockIdx.x*256+threadIdx.x;
  if(i<NE) atomicAdd(&counts[eidx[NE+i]], 1);
  if(i<NN) atomicAdd(&cntg[batch[i]], 1);
}
__global__ void k_scan1(const int* __restrict__ counts, int* __restrict__ bsums){
  __shared__ int red[256];
  int b=blockIdx.x, t=threadIdx.x;
  int base=b*512;
  int v=0;
  for(int i=t;i<512;i+=256){ int g=base+i; if(g<NN) v+=counts[g]; }
  red[t]=v; __syncthreads();
  for(int s=128;s;s>>=1){ if(t<s) red[t]+=red[t+s]; __syncthreads(); }
  if(t==0) bsums[b]=red[0];
}
__global__ void k_scan23(const int* __restrict__ counts, const int* __restrict__ bsums,
                         int* __restrict__ offs, int* __restrict__ cursor){
  __shared__ int c_l[512];
  int b=blockIdx.x, t=threadIdx.x, base=b*512;
  for(int i=t;i<512;i+=256){ int g=base+i; c_l[i] = (g<NN)? counts[g]:0; }
  __syncthreads();
  if(t==0){
    int run=0;
    for(int i=0;i<b;i++) run += bsums[i];
    for(int i=0;i<512;i++){
      int g=base+i;
      if(g<NN){ offs[g]=run; cursor[g]=run; }
      run += c_l[i];
    }
    if(b==39) offs[NN]=run;
  }
}
__global__ void k_fill(const int* __restrict__ eidx, int* __restrict__ cursor,
                       const float* __restrict__ eattr,
                       int* __restrict__ srcp, float* __restrict__ ea_s){
  int e = blockIdx.x*256+threadIdx.x;
  if(e>=NE) return;
  int d = eidx[NE+e];
  int s = eidx[e];
  int pos = atomicAdd(&cursor[d], 1);
  srcp[pos] = s;
  const float4* src4 = reinterpret_cast<const float4*>(eattr + (size_t)e*16);
  float4* dst4 = reinterpret_cast<float4*>(ea_s + (size_t)pos*16);
  dst4[0]=src4[0]; dst4[1]=src4[1]; dst4[2]=src4[2]; dst4[3]=src4[3];
}

// P_a/P_b + per-node small precomputes (G, V) in one kernel.
__global__ __launch_bounds__(256,4) void k_pre(
                      const float* __restrict__ node_s, const float* __restrict__ node_v,
                      const float* __restrict__ Wt_ss, const float* __restrict__ Wt_vs,
                      const float* __restrict__ Wsv, const float* __restrict__ Wvv,
                      float* __restrict__ P_a, float* __restrict__ P_b,
                      float* __restrict__ G_a, float* __restrict__ G_b,
                      float* __restrict__ V_a, float* __restrict__ V_b){
  __shared__ float s_l[16][128];
  __shared__ float nv_l[16][4];
  __shared__ float uv[16][12];
  int t = threadIdx.x;
  int n0 = blockIdx.x*16;
  for(int idx=t; idx<2048; idx+=256){
    int n = idx>>7, k = idx&127;
    s_l[n][k] = node_s[(size_t)(n0+n)*128 + k];
  }
  if(t<192){ int n=t/12, k=t%12; uv[n][k] = node_v[(n0+n)*12+k]; }
  __syncthreads();
  if(t<64){
    int n=t>>2, j=t&3;
    float x=uv[n][j*3], y=uv[n][j*3+1], z=uv[n][j*3+2];
    float n2=x*x+y*y+z*z;
    nv_l[n][j] = n2>0.f ? sqrtf(n2) : 0.f;
  }
  if(t<192){
    int n=t/12, k=t%12, c=k/3, x=k-c*3;
    float va=0.f, vb=0.f;
#pragma unroll
    for(int j=0;j<4;j++){
      float vv = uv[n][j*3+x];
      va += Wvv[c*9+j]*vv;
      vb += Wvv[c*9+4+j]*vv;
    }
    V_a[(n0+n)*12+k]=va; V_b[(n0+n)*12+k]=vb;
  }
  if(t<128){
    int n=t>>3, c=(t>>1)&3, hh=t&1;
    const float* w = Wsv + c*384 + hh*128;
    float g=0.f;
    for(int k=0;k<128;k+=4){
      float4 s4 = *reinterpret_cast<const float4*>(&s_l[n][k]);
      g = fmaf(s4.x,w[k],g); g = fmaf(s4.y,w[k+1],g);
      g = fmaf(s4.z,w[k+2],g); g = fmaf(s4.w,w[k+3],g);
    }
    (hh ? G_b : G_a)[(n0+n)*4+c] = g;
  }
  __syncthreads();
  int o = t&127, h = t>>7;
  float acc[16];
#pragma unroll
  for(int i=0;i<16;i++) acc[i]=0.f;
  const float* Wb = Wt_ss + h*128*128;
  for(int k=0;k<128;k+=4){
    float w0=Wb[(k+0)*128+o], w1=Wb[(k+1)*128+o], w2=Wb[(k+2)*128+o], w3=Wb[(k+3)*128+o];
#pragma unroll
    for(int n=0;n<16;n++){
      float4 s4 = *reinterpret_cast<const float4*>(&s_l[n][k]);
      acc[n] = fmaf(s4.x,w0,acc[n]); acc[n] = fmaf(s4.y,w1,acc[n]);
      acc[n] = fmaf(s4.z,w2,acc[n]); acc[n] = fmaf(s4.w,w3,acc[n]);
    }
  }
  const float* Wv = Wt_vs + h*4*128;
#pragma unroll
  for(int j=0;j<4;j++){
    float w = Wv[j*128+o];
#pragma unroll
    for(int n=0;n<16;n++) acc[n] += nv_l[n][j]*w;
  }
  float* P = h ? P_b : P_a;
#pragma unroll
  for(int n=0;n<16;n++) P[(size_t)(n0+n)*128+o] = acc[n];
}

// edge-path constants folded through edge_proj, all 3 layers in one launch
__global__ void k_econst3(const float* __restrict__ mWss, const float* __restrict__ mWvs,
                          const float* __restrict__ mWsv, const float* __restrict__ mWvv,
                          const float* __restrict__ Wep, const float* __restrict__ epb,
                          float* __restrict__ econ){
  int l = blockIdx.x;
  const float* Wss = mWss + (size_t)l*128*384;
  const float* Wvs = mWvs + (size_t)l*128*9;
  const float* Wsv = mWsv + (size_t)l*4*384;
  const float* Wvv = mWvv + (size_t)l*4*9;
  float* ec = econ + (size_t)l*2048;
  int t=threadIdx.x;
  for(int idx=t; idx<13*128; idx+=256){
    int j=idx>>7, o=idx&127;
    float s=0.f;
    for(int k=0;k<128;k++) s += Wss[o*384+256+k]*Wep[k*13+j];
    ec[j*128+o]=s;
  }
  for(int o=t;o<128;o+=256){
    float s=0.f;
    for(int k=0;k<128;k++) s += Wss[o*384+256+k]*epb[k];
    ec[1664+o]=s;
    ec[1792+o]=Wvs[o*9+8];
  }
  if(t<52){ int c=t/13,j=t%13; float s=0.f; for(int k=0;k<128;k++) s+=Wsv[c*384+256+k]*Wep[k*13+j]; ec[1920+t]=s; }
  if(t<4){ float s=0.f; for(int k=0;k<128;k++) s+=Wsv[t*384+256+k]*epb[k]; ec[1972+t]=s; ec[1976+t]=Wvv[t*9+8]; }
}

// per-layer edge precompute: preS2[pos] = packed bf16 pair; preG[pos] = {gate[4], ev[3], 0}
// (r8 body restored: size_t indexing — r9's int32 indexing regressed 166->300us, A/B revert)
__global__ __launch_bounds__(256,4) void k_edge(
    const float* __restrict__ ea_s, const float* __restrict__ ec,
    unsigned* __restrict__ preS2, float* __restrict__ preG){
  int t = threadIdx.x;
  int lane = t&63;
  int wid = blockIdx.x*4 + (t>>6);
  float mex[13], mey[13];
#pragma unroll
  for(int j=0;j<13;j++){ mex[j]=ec[j*128+lane]; mey[j]=ec[j*128+64+lane]; }
  float bx=ec[1664+lane], by=ec[1664+64+lane];
  float w8x=ec[1792+lane], w8y=ec[1792+64+lane];
  int cg = (lane<4)?lane:0;
  float grc[13];
#pragma unroll
  for(int j=0;j<13;j++) grc[j]=ec[1920+cg*13+j];
  float gb = ec[1972+cg];
  int e00 = wid*8;
#pragma unroll 2
  for(int i=0;i<8;i++){
    int e = e00+i;
    const float4* ea = reinterpret_cast<const float4*>(ea_s + (size_t)e*16);
    float4 A0=ea[0], A1=ea[1], A2=ea[2], A3=ea[3];
    float e0=A0.x,e1=A0.y,e2=A1.y,e3=A1.z,e4=A1.w,
          e5=A2.x,e6=A2.y,e7=A2.z,e8=A2.w,e9=A3.x,
          e10=A3.y,e11=A3.z,e12=A3.w;
    float evx=A0.z, evy=A0.w, evz=A1.x;
    float en2 = evx*evx+evy*evy+evz*evz;
    float evn = en2>0.f ? sqrtf(en2) : 0.f;
    float px = fmaf(evn,w8x,bx);
    float py = fmaf(evn,w8y,by);
    px=fmaf(mex[0],e0,px);   py=fmaf(mey[0],e0,py);
    px=fmaf(mex[1],e1,px);   py=fmaf(mey[1],e1,py);
    px=fmaf(mex[2],e2,px);   py=fmaf(mey[2],e2,py);
    px=fmaf(mex[3],e3,px);   py=fmaf(mey[3],e3,py);
    px=fmaf(mex[4],e4,px);   py=fmaf(mey[4],e4,py);
    px=fmaf(mex[5],e5,px);   py=fmaf(mey[5],e5,py);
    px=fmaf(mex[6],e6,px);   py=fmaf(mey[6],e6,py);
    px=fmaf(mex[7],e7,px);   py=fmaf(mey[7],e7,py);
    px=fmaf(mex[8],e8,px);   py=fmaf(mey[8],e8,py);
    px=fmaf(mex[9],e9,px);   py=fmaf(mey[9],e9,py);
    px=fmaf(mex[10],e10,px); py=fmaf(mey[10],e10,py);
    px=fmaf(mex[11],e11,px); py=fmaf(mey[11],e11,py);
    px=fmaf(mex[12],e12,px); py=fmaf(mey[12],e12,py);
    preS2[(size_t)e*64+lane] = bf_rne(px) | (bf_rne(py)<<16);
    if(lane<4){
      float g=gb;
      g=fmaf(grc[0],e0,g);  g=fmaf(grc[1],e1,g);  g=fmaf(grc[2],e2,g);
      g=fmaf(grc[3],e3,g);  g=fmaf(grc[4],e4,g);  g=fmaf(grc[5],e5,g);
      g=fmaf(grc[6],e6,g);  g=fmaf(grc[7],e7,g);  g=fmaf(grc[8],e8,g);
      g=fmaf(grc[9],e9,g);  g=fmaf(grc[10],e10,g); g=fmaf(grc[11],e11,g);
      g=fmaf(grc[12],e12,g);
      preG[(size_t)e*8+lane] = g;
    } else if(lane<7){
      float evv = (lane==4)?evx:((lane==5)?evy:evz);
      preG[(size_t)e*8+lane] = evv;
    }
  }
}

// skinny gather kernel: one wave per destination node (int32 indices, high occupancy)
#define DECLST(P) unsigned P##w=0; float P##pax=0.f,P##pay=0.f,P##g8=0.f,P##ev=0.f,P##ga=0.f,P##va=0.f;
#define LOADST(P, IDX) do{ int _p=(IDX); int _s=srcp[_p]; \
  P##w   = preS2[_p*64 + lane]; \
  P##pax = P_a[_s*128+lane]; P##pay = P_a[_s*128+64+lane]; \
  if(lane<12){ P##g8 = preG[_p*8+cv]; P##ev = preG[_p*8+4+xv]; \
               P##ga = G_a[_s*4+cv];  P##va = V_a[_s*12+lane]; } \
}while(0)
#define COMPUTE(P) do{ \
  float px = __uint_as_float(P##w<<16); \
  float py = __uint_as_float(P##w & 0xffff0000u); \
  float pre0 = px + P##pax + PBx; \
  float pre1 = py + P##pay + PBy; \
  float sm = pre0+pre1; \
  float sq = pre0*pre0 + pre1*pre1; \
  _Pragma("unroll") \
  for(int m=32;m;m>>=1){ sm += __shfl_xor(sm,m); sq += __shfl_xor(sq,m); } \
  float mean = sm*0.0078125f; \
  float var  = fmaf(sq,0.0078125f, -mean*mean); \
  float rstd = rsqrtf((var>0.f?var:0.f) + 1e-5f); \
  accx += gelu_t(fmaf((pre0-mean)*rstd, LGx, LBx)); \
  accy += gelu_t(fmaf((pre1-mean)*rstd, LGy, LBy)); \
  if(lane<12){ \
    float g = P##g8 + P##ga + gbn; \
    float gt = sigm_f(g); \
    avk = fmaf(fmaf(wvc, P##ev, P##va + vbk), gt, avk); \
  } \
}while(0)

__global__ __launch_bounds__(256,8) void k_msg(
                      const float* __restrict__ P_a, const float* __restrict__ P_b,
                      const float* __restrict__ G_a, const float* __restrict__ G_b,
                      const float* __restrict__ V_a, const float* __restrict__ V_b,
                      const unsigned* __restrict__ preS2, const float* __restrict__ preG,
                      const int* __restrict__ srcp, const int* __restrict__ offs,
                      const float* __restrict__ ec,
                      const float* __restrict__ lng, const float* __restrict__ lnb,
                      float* __restrict__ ag_s, float* __restrict__ ag_v){
  int t = threadIdx.x;
  int n = blockIdx.x*4 + (t>>6);
  int lane = t&63;
  float PBx = P_b[n*128+lane], PBy = P_b[n*128+64+lane];
  float LGx = lng[lane], LGy = lng[64+lane];
  float LBx = lnb[lane], LBy = lnb[64+lane];
  int cv = lane/3, xv = lane - cv*3;
  float vbk=0.f, gbn=0.f, wvc=0.f;
  if(lane<12){
    vbk = V_b[n*12+lane];
    gbn = G_b[n*4+cv];
    wvc = ec[1976+cv];
  }
  float accx=0.f, accy=0.f, avk=0.f;
  int beg = offs[n], end = offs[n+1];
  DECLST(a_) DECLST(b_)
  int idx = beg;
  if(beg < end) LOADST(a_, beg);
  while(idx + 1 < end){
    LOADST(b_, idx+1);
    COMPUTE(a_);
    if(idx + 2 < end) LOADST(a_, idx+2);
    COMPUTE(b_);
    idx += 2;
  }
  if(idx < end) COMPUTE(a_);
  ag_s[n*128+lane]    = accx;
  ag_s[n*128+64+lane] = accy;
  if(lane<12) ag_v[n*12+lane] = avk;
}

// node update GVP (residual)
__global__ __launch_bounds__(256,4) void k_update(
                         float* __restrict__ node_s, float* __restrict__ node_v,
                         const float* __restrict__ ag_s, const float* __restrict__ ag_v,
                         const float* __restrict__ Wt_ss, const float* __restrict__ Wt_vs,
                         const float* __restrict__ Wsv, const float* __restrict__ Wvv,
                         const float* __restrict__ lng, const float* __restrict__ lnb){
  __shared__ float us[16][260];
  __shared__ float pre[16][129];
  __shared__ float uv[16][24];
  __shared__ float uvn[16][8];
  __shared__ float stats[16][2];
  __shared__ float gate_l[16][4];
  int t = threadIdx.x;
  int n0 = blockIdx.x*16;
  for(int idx=t; idx<2048; idx+=256){
    int n = idx>>7, k = idx&127;
    us[n][k]     = node_s[(size_t)(n0+n)*128+k];
    us[n][128+k] = ag_s[(size_t)(n0+n)*128+k];
  }
  for(int idx=t; idx<384; idx+=256){
    int n = idx/24, k = idx%24;
    uv[n][k] = (k<12) ? node_v[(n0+n)*12+k] : ag_v[(n0+n)*12 + (k-12)];
  }
  __syncthreads();
  if(t<128){
    int n=t>>3, j=t&7;
    float x=uv[n][j*3], y=uv[n][j*3+1], z=uv[n][j*3+2];
    float n2=x*x+y*y+z*z;
    uvn[n][j] = n2>0.f ? sqrtf(n2) : 0.f;
  }
  __syncthreads();
  int o = t&127, h = t>>7;
  float acc[8];
#pragma unroll
  for(int i=0;i<8;i++) acc[i]=0.f;
  for(int k=0;k<256;k+=4){
    float w0=Wt_ss[(k+0)*128+o], w1=Wt_ss[(k+1)*128+o], w2=Wt_ss[(k+2)*128+o], w3=Wt_ss[(k+3)*128+o];
#pragma unroll
    for(int i=0;i<8;i++){
      float4 s4 = *reinterpret_cast<const float4*>(&us[h*8+i][k]);
      acc[i] = fmaf(s4.x,w0,acc[i]); acc[i] = fmaf(s4.y,w1,acc[i]);
      acc[i] = fmaf(s4.z,w2,acc[i]); acc[i] = fmaf(s4.w,w3,acc[i]);
    }
  }
#pragma unroll
  for(int j=0;j<8;j++){
    float w = Wt_vs[j*128+o];
#pragma unroll
    for(int i=0;i<8;i++) acc[i] += uvn[h*8+i][j]*w;
  }
#pragma unroll
  for(int i=0;i<8;i++) pre[h*8+i][o] = acc[i];
  __syncthreads();
  {
    int n = t>>4, p = t&15;
    float s=0.f;
#pragma unroll
    for(int q=0;q<8;q++) s += pre[n][p*8+q];
#pragma unroll
    for(int m=8;m;m>>=1) s += __shfl_xor(s,m);
    float mean = s*(1.f/128.f);
    float v=0.f;
#pragma unroll
    for(int q=0;q<8;q++){ float d=pre[n][p*8+q]-mean; v += d*d; }
#pragma unroll
    for(int m=8;m;m>>=1) v += __shfl_xor(v,m);
    if(p==0){ stats[n][0]=mean; stats[n][1]=rsqrtf(v*(1.f/128.f)+1e-5f); }
  }
  __syncthreads();
  {
    float LG = lng[o], LB = lnb[o];
#pragma unroll
    for(int i=0;i<8;i++){
      int n = h*8+i;
      float hh = (pre[n][o]-stats[n][0])*stats[n][1]*LG + LB;
      node_s[(size_t)(n0+n)*128+o] += gelu_f(hh);
    }
  }
  {
    int n = t>>4, c = t&3, p = (t>>2)&3;
    float g=0.f;
    int kb = p*64;
    for(int k=0;k<64;k+=4){
      float4 s4 = *reinterpret_cast<const float4*>(&us[n][kb+k]);
      g = fmaf(s4.x,Wsv[c*256+kb+k],g);   g = fmaf(s4.y,Wsv[c*256+kb+k+1],g);
      g = fmaf(s4.z,Wsv[c*256+kb+k+2],g); g = fmaf(s4.w,Wsv[c*256+kb+k+3],g);
    }
    g += __shfl_xor(g,4);
    g += __shfl_xor(g,8);
    if(p==0) gate_l[n][c] = sigm(g);
  }
  __syncthreads();
  if(t<192){
    int n = t/12, k = t%12, c = k/3, x = k-c*3;
    float s=0.f;
#pragma unroll
    for(int j=0;j<8;j++) s += Wvv[c*8+j]*uv[n][j*3+x];
    node_v[(n0+n)*12+k] += s*gate_l[n][c];
  }
}

// updated_nodes = node_s @ noW.T + b ; block = 32 rows x 256 cols, thread = 8n x 4o.
__global__ __launch_bounds__(256,8) void k_out(
    const float* __restrict__ node_s, const float* __restrict__ Wt_no,
    const float* __restrict__ nob, float* __restrict__ out){
  __shared__ float s_l[32][132];
  int t = threadIdx.x;
  int n0 = blockIdx.x*32;
  int oc0 = blockIdx.y*256;
  {
    const float4* g = reinterpret_cast<const float4*>(node_s + (size_t)n0*128);
    for(int i=t;i<1024;i+=256){
      int n=i>>5, kq=i&31;
      *reinterpret_cast<float4*>(&s_l[n][kq*4]) = g[i];
    }
  }
  __syncthreads();
  int oq = t&63, ng = t>>6;
  int o = oc0 + oq*4;
  float4 acc[8];
#pragma unroll
  for(int i=0;i<8;i++) acc[i]=float4{0.f,0.f,0.f,0.f};
  for(int k=0;k<128;k+=4){
    float4 w0 = *reinterpret_cast<const float4*>(&Wt_no[(k+0)*1280+o]);
    float4 w1 = *reinterpret_cast<const float4*>(&Wt_no[(k+1)*1280+o]);
    float4 w2 = *reinterpret_cast<const float4*>(&Wt_no[(k+2)*1280+o]);
    float4 w3 = *reinterpret_cast<const float4*>(&Wt_no[(k+3)*1280+o]);
#pragma unroll
    for(int i=0;i<8;i++){
      float4 s = *reinterpret_cast<const float4*>(&s_l[ng*8+i][k]);
      acc[i].x=fmaf(s.x,w0.x,acc[i].x); acc[i].y=fmaf(s.x,w0.y,acc[i].y);
      acc[i].z=fmaf(s.x,w0.z,acc[i].z); acc[i].w=fmaf(s.x,w0.w,acc[i].w);
      acc[i].x=fmaf(s.y,w1.x,acc[i].x); acc[i].y=fmaf(s.y,w1.y,acc[i].y);
      acc[i].z=fmaf(s.y,w1.z,acc[i].z); acc[i].w=fmaf(s.y,w1.w,acc[i].w);
      acc[i].x=fmaf(s.z,w2.x,acc[i].x); acc[i].y=fmaf(s.z,w2.y,acc[i].y);
      acc[i].z=fmaf(s.z,w2.z,acc[i].z); acc[i].w=fmaf(s.z,w2.w,acc[i].w);
      acc[i].x=fmaf(s.w,w3.x,acc[i].x); acc[i].y=fmaf(s.w,w3.y,acc[i].y);
      acc[i].z=fmaf(s.w,w3.z,acc[i].z); acc[i].w=fmaf(s.w,w3.w,acc[i].w);
    }
  }
  float4 b4 = *reinterpret_cast<const float4*>(&nob[o]);
#pragma unroll
  for(int i=0;i<8;i++){
    int row = n0 + ng*8 + i;
    float4 r{acc[i].x+b4.x, acc[i].y+b4.y, acc[i].z+b4.z, acc[i].w+b4.w};
    *reinterpret_cast<float4*>(&out[16384 + (size_t)row*1280 + o]) = r;
  }
}

// graph-feature partial sums (sorted-run compressed atomics)
__global__ __launch_bounds__(256,4) void k_gfeat(
                        const float* __restrict__ node_s, const float* __restrict__ Wt,
                        const int* __restrict__ batch, float* __restrict__ gacc){
  __shared__ float s_l[16][128];
  __shared__ int b_l[16];
  int t=threadIdx.x, n0=blockIdx.x*16;
  for(int idx=t; idx<2048; idx+=256){ int n=idx>>7,k=idx&127; s_l[n][k]=node_s[(size_t)(n0+n)*128+k]; }
  if(t<16) b_l[t]=batch[n0+t];
  __syncthreads();
  int o=t;
  float acc[16];
#pragma unroll
  for(int i=0;i<16;i++) acc[i]=0.f;
  for(int k=0;k<128;k+=4){
    float w0=Wt[(k+0)*256+o], w1=Wt[(k+1)*256+o], w2=Wt[(k+2)*256+o], w3=Wt[(k+3)*256+o];
#pragma unroll
    for(int n=0;n<16;n++){
      float4 s4 = *reinterpret_cast<const float4*>(&s_l[n][k]);
      acc[n] = fmaf(s4.x,w0,acc[n]); acc[n] = fmaf(s4.y,w1,acc[n]);
      acc[n] = fmaf(s4.z,w2,acc[n]); acc[n] = fmaf(s4.w,w3,acc[n]);
    }
  }
  float run=0.f; int cur=b_l[0];
#pragma unroll
  for(int n=0;n<16;n++){
    int g=b_l[n];
    if(g!=cur){ atomicAdd(&gacc[cur*256+o], run); run=0.f; cur=g; }
    run += acc[n];
  }
  atomicAdd(&gacc[cur*256+o], run);
}

__global__ void k_gfin(const float* __restrict__ gacc, const int* __restrict__ cntg,
                       const float* __restrict__ gob, float* __restrict__ out){
  int g=blockIdx.x, o=threadIdx.x;
  int c=cntg[g];
  out[g*256+o] = (c>0) ? (gacc[g*256+o]/(float)c + gob[o]) : 0.f;
}

} // namespace

extern "C" void kernel_launch(void* const* d_in, const int* in_sizes, int n_in,
                              void* d_out, int out_size, void* d_ws, size_t ws_size,
                              hipStream_t stream){
  (void)in_sizes; (void)n_in; (void)out_size;
  const float* esm   = (const float*)d_in[0];
  const float* geo   = (const float*)d_in[1];
  const float* coords= (const float*)d_in[2];
  const int*   eidx  = (const int*)d_in[3];
  const float* eattr = (const float*)d_in[4];
  const int*   batch = (const int*)d_in[5];
  const float* npW   = (const float*)d_in[6];
  const float* npb   = (const float*)d_in[7];
  const float* epW   = (const float*)d_in[8];
  const float* epb   = (const float*)d_in[9];
  const float* mWss  = (const float*)d_in[10];
  const float* mWvs  = (const float*)d_in[11];
  const float* mWsv  = (const float*)d_in[12];
  const float* mWvv  = (const float*)d_in[13];
  const float* mlg   = (const float*)d_in[14];
  const float* mlb   = (const float*)d_in[15];
  const float* uWss  = (const float*)d_in[16];
  const float* uWvs  = (const float*)d_in[17];
  const float* uWsv  = (const float*)d_in[18];
  const float* uWvv  = (const float*)d_in[19];
  const float* ulg   = (const float*)d_in[20];
  const float* ulb   = (const float*)d_in[21];
  const float* noW   = (const float*)d_in[22];
  const float* nob   = (const float*)d_in[23];
  const float* goW   = (const float*)d_in[24];
  const float* gob   = (const float*)d_in[25];
  float* out = (float*)d_out;

  char* base = (char*)d_ws;
  size_t off = 0;
  auto ALLOC = [&](size_t bytes)->char*{
    char* p = base + off;
    off = (off + bytes + 255) & ~(size_t)255;
    return p;
  };
  float* node_s = (float*)ALLOC((size_t)NN*128*4);
  float* P_a    = (float*)ALLOC((size_t)NN*128*4);
  float* P_b    = (float*)ALLOC((size_t)NN*128*4);
  float* ag_s   = (float*)ALLOC((size_t)NN*128*4);
  float* node_v = (float*)ALLOC((size_t)NN*12*4);
  float* ag_v   = (float*)ALLOC((size_t)NN*12*4);
  float* V_a    = (float*)ALLOC((size_t)NN*12*4);
  float* V_b    = (float*)ALLOC((size_t)NN*12*4);
  float* G_a    = (float*)ALLOC((size_t)NN*4*4);
  float* G_b    = (float*)ALLOC((size_t)NN*4*4);
  unsigned short* npW_bf = (unsigned short*)ALLOC((size_t)128*1408*2);
  unsigned short* esm_bf = (unsigned short*)ALLOC((size_t)NN*1408*2);
  float* Wt_no  = (float*)ALLOC((size_t)128*1280*4);
  float* Wt_go  = (float*)ALLOC((size_t)128*256*4);
  float* Wt_mss = (float*)ALLOC((size_t)3*256*128*4);
  float* Wt_mvs = (float*)ALLOC((size_t)3*9*128*4);
  float* Wt_uss = (float*)ALLOC((size_t)3*256*128*4);
  float* Wt_uvs = (float*)ALLOC((size_t)3*8*128*4);
  float* econ   = (float*)ALLOC((size_t)3*2048*4);
  float* gacc   = (float*)ALLOC((size_t)64*256*4);
  int* counts = (int*)ALLOC((size_t)NN*4);
  int* offs   = (int*)ALLOC((size_t)(NN+1)*4);
  int* cursor = (int*)ALLOC((size_t)NN*4);
  int* bsums  = (int*)ALLOC((size_t)64*4);
  int* cntg   = (int*)ALLOC((size_t)64*4);
  int* srcp   = (int*)ALLOC((size_t)NE*4);
  float* ea_s = (float*)ALLOC((size_t)NE*16*4);
  unsigned* preS2 = (unsigned*)ALLOC((size_t)NE*64*4);
  float* preG     = (float*)ALLOC((size_t)NE*8*4);
  if(off > ws_size) return;
  // k-split partials alias preS2 (consumed by k_reduce before k_edge writes preS2)
  float* part = (float*)preS2;

  hipMemsetAsync(gacc, 0, (size_t)64*256*4, stream);

  k_prep<<<2267,256,0,stream>>>(npW, noW, goW, mWss, mWvs, uWss, uWvs,
                                npW_bf, Wt_no, Wt_go, Wt_mss, Wt_mvs, Wt_uss, Wt_uvs);
  k_conv<<<13750,256,0,stream>>>(esm, geo, esm_bf);
  k_init<<<1252,256,0,stream>>>(esm_bf, npW_bf, part);
  k_reduce<<<10000,256,0,stream>>>(part, npb, node_s);
  k_nodevec<<<79,256,0,stream>>>(coords, geo, node_v, counts, cntg);
  k_hist<<<2500,256,0,stream>>>(eidx, batch, counts, cntg);
  k_scan1<<<40,256,0,stream>>>(counts, bsums);
  k_scan23<<<40,256,0,stream>>>(counts, bsums, offs, cursor);
  k_fill<<<2500,256,0,stream>>>(eidx, cursor, eattr, srcp, ea_s);
  k_econst3<<<3,256,0,stream>>>(mWss, mWvs, mWsv, mWvv, epW, epb, econ);

  for(int l=0;l<3;l++){
    k_pre<<<1250,256,0,stream>>>(node_s, node_v,
                                 Wt_mss + (size_t)l*256*128, Wt_mvs + (size_t)l*9*128,
                                 mWsv + (size_t)l*4*384, mWvv + (size_t)l*4*9,
                                 P_a, P_b, G_a, G_b, V_a, V_b);
    k_edge<<<20000,256,0,stream>>>(ea_s, econ + (size_t)l*2048, preS2, preG);
    k_msg<<<5000,256,0,stream>>>(P_a, P_b, G_a, G_b, V_a, V_b, preS2, preG, srcp, offs,
                                 econ + (size_t)l*2048, mlg + (size_t)l*128, mlb + (size_t)l*128,
                                 ag_s, ag_v);
    k_update<<<1250,256,0,stream>>>(node_s, node_v, ag_s, ag_v,
                                    Wt_uss + (size_t)l*256*128, Wt_uvs + (size_t)l*8*128,
                                    uWsv + (size_t)l*4*256, uWvv + (size_t)l*4*8,
                                    ulg + (size_t)l*128, ulb + (size_t)l*128);
  }
  k_out<<<dim3(625,5),256,0,stream>>>(node_s, Wt_no, nob, out);
  k_gfeat<<<1250,256,0,stream>>>(node_s, Wt_go, batch, gacc);
  k_gfin<<<64,256,0,stream>>>(gacc, cntg, gob, out);
}